// Round 12
// baseline (67.620 us; speedup 1.0000x reference)
//
#include <hip/hip_runtime.h>
#include <math.h>

typedef __attribute__((ext_vector_type(2))) _Float16 half2v;
typedef __attribute__((ext_vector_type(2))) float f32x2;
typedef __attribute__((ext_vector_type(4), aligned(8))) unsigned int uint4a;

#define BB 4
#define HH 2048
#define WW 128
#define HP (HH + 2)   // 2050
#define WP (WW + 2)   // 130
#define PP 128        // pooled size
#define ROWS 4

#define BORDER_PER_B (2 * WP + 2 * (HP - 2))   // 4356

__device__ __forceinline__ half2v b2h(unsigned u) { return __builtin_bit_cast(half2v, u); }
__device__ __forceinline__ unsigned pku(float a, float b) {
    return __builtin_bit_cast(unsigned, __builtin_amdgcn_cvt_pkrtz(a, b));
}
__device__ __forceinline__ float dot2(half2v a, unsigned wb, float c) {
    return __builtin_amdgcn_fdot2(a, b2h(wb), c, false);
}
__device__ __forceinline__ float hlo(unsigned u) { return (float)b2h(u).x; }
__device__ __forceinline__ float hhi(unsigned u) { return (float)b2h(u).y; }

// Shared XCD swizzle: 2048 blocks, XCD k (= bid%8, round-robin dispatch) owns
// swz in [k*256, (k+1)*256) = one contiguous 1024-row span of one batch.
// Used by BOTH k_mat (producer) and k_deform (consumer) -> xph stays in the
// producing XCD's L2 (per-XCD L2s are not cross-coherent; mismatched mappings
// forced ~2.5x HBM re-fetch, R10: FETCH 21MB vs 8.6MB compulsory).
__device__ __forceinline__ void swz_map(int bid, int* b, int* h0) {
    int swz = (bid & 7) * 256 + (bid >> 3);
    *b = swz >> 9;
    *h0 = (swz & 511) * 4;
}

// ---------------------------------------------------------------------------
// Kernel 1: border-zero of xph (fused) + adaptive avg pool + 1x1 conv + sigmoid
// ---------------------------------------------------------------------------
__global__ void k_fm(const float* __restrict__ rgb, const float* __restrict__ w_fm,
                     float* __restrict__ fm, uint2* __restrict__ xph) {
    int j = threadIdx.x;              // 0..127
    int bi = blockIdx.x;              // b*128 + i
    int tid = bi * 128 + j;

    if (tid < BB * BORDER_PER_B) {
        int b = tid / BORDER_PER_B;
        int r = tid - b * BORDER_PER_B;
        int row, col;
        if (r < WP)          { row = 0;      col = r; }
        else if (r < 2 * WP) { row = HP - 1; col = r - WP; }
        else {
            int q = r - 2 * WP;
            row = 1 + (q >> 1);
            col = (q & 1) ? (WP - 1) : 0;
        }
        xph[((size_t)b * HP + row) * WP + col] = make_uint2(0u, 0u);
    }

    int b = bi >> 7, i = bi & 127;
    const float* r0 = rgb + ((size_t)(b * 2 + 0) * HH + (size_t)i * 16) * WW + j;
    const float* r1 = rgb + ((size_t)(b * 2 + 1) * HH + (size_t)i * 16) * WW + j;
    float s0 = 0.f, s1 = 0.f;
#pragma unroll
    for (int a = 0; a < 16; ++a) { s0 += r0[a * WW]; s1 += r1[a * WW]; }
    s0 *= (1.f / 16.f); s1 *= (1.f / 16.f);
    float f0 = w_fm[0] * s0 + w_fm[1] * s1;
    float f1 = w_fm[2] * s0 + w_fm[3] * s1;
    fm[((size_t)(b * 2 + 0) * PP + i) * PP + j] = 1.f / (1.f + expf(-f0));
    fm[((size_t)(b * 2 + 1) * PP + i) * PP + j] = 1.f / (1.f + expf(-f1));
}

// ---------------------------------------------------------------------------
// Kernel 2: mat = rgb @ fm + rgb (per b,c), fs = w_fs @ mat,
//           pack xph cell = f16x4 (sar0,sar1,fs0,fs1) as uint2 (8B).
// Block mapping via swz_map (XCD co-location with k_deform).
// ---------------------------------------------------------------------------
__global__ __launch_bounds__(128) void k_mat(
        const float* __restrict__ rgb, const float* __restrict__ sar,
        const float* __restrict__ w_fs, const float* __restrict__ fm,
        uint2* __restrict__ xph) {
    int w = threadIdx.x;              // 0..127
    int b, h0;
    swz_map(blockIdx.x, &b, &h0);

    const float* rg0 = rgb + ((size_t)(b * 2 + 0) * HH + h0) * WW;  // uniform base
    const float* rg1 = rgb + ((size_t)(b * 2 + 1) * HH + h0) * WW;
    const float* fm0 = fm + (size_t)(b * 2 + 0) * PP * PP;
    const float* fm1 = fm + (size_t)(b * 2 + 1) * PP * PP;

    float acc0[ROWS], acc1[ROWS];
#pragma unroll
    for (int r = 0; r < ROWS; ++r) {                 // residual term
        acc0[r] = rg0[r * WW + w];
        acc1[r] = rg1[r * WW + w];
    }

#pragma unroll 4
    for (int k4 = 0; k4 < PP; k4 += 4) {
        float f0[4], f1[4];
#pragma unroll
        for (int t = 0; t < 4; ++t) {
            f0[t] = fm0[(size_t)(k4 + t) * PP + w];  // coalesced vector load
            f1[t] = fm1[(size_t)(k4 + t) * PP + w];
        }
#pragma unroll
        for (int r = 0; r < ROWS; ++r) {
            float4 a0 = *(const float4*)(rg0 + r * WW + k4);   // uniform -> s_load
            float4 a1 = *(const float4*)(rg1 + r * WW + k4);
            acc0[r] += a0.x * f0[0] + a0.y * f0[1] + a0.z * f0[2] + a0.w * f0[3];
            acc1[r] += a1.x * f1[0] + a1.y * f1[1] + a1.z * f1[2] + a1.w * f1[3];
        }
    }

    float wa = w_fs[0], wb = w_fs[1], wc = w_fs[2], wd = w_fs[3];
#pragma unroll
    for (int r = 0; r < ROWS; ++r) {
        float m0 = acc0[r], m1 = acc1[r];
        float fs0 = wa * m0 + wb * m1;
        float fs1 = wc * m0 + wd * m1;
        float s0 = sar[((size_t)(b * 2 + 0) * HH + (h0 + r)) * WW + w];
        float s1 = sar[((size_t)(b * 2 + 1) * HH + (h0 + r)) * WW + w];
        uint2 cell = make_uint2(pku(s0, s1), pku(fs0, fs1));
        xph[((size_t)b * HP + (h0 + r + 1)) * WP + (w + 1)] = cell;
    }
}

// ---------------------------------------------------------------------------
// Kernel 3: offset conv (f32 pk_fma, exact offsets) + deformable bilinear in
// f16 (paired-row 16B gathers + cndmask x-select, dot2 combine). 2 px/thread.
// Same swz_map as k_mat -> all xph gathers are same-XCD L2 hits.
// ---------------------------------------------------------------------------
__global__ __launch_bounds__(256, 3) void k_deform(
        const float* __restrict__ w_p, const float* __restrict__ b_p,
        const float* __restrict__ w_dc, const uint2* __restrict__ xph,
        float* __restrict__ out) {
    int b, h0;
    swz_map(blockIdx.x, &b, &h0);
    int tid = threadIdx.x;
    int w = tid & 127;
    int h = h0 + ((tid >> 7) << 1);             // this thread: rows h, h+1

    const uint2* xb = xph + (size_t)b * HP * WP;          // SGPR base
    const unsigned* xbu = (const unsigned*)xb;
    float* outb = out + (size_t)(b * 2) * HH * WW;        // SGPR base

    // 4 rows x 3 cols f16 neighborhood (8B cells)
    uint2 nbc[4][3];
#pragma unroll
    for (int dy = 0; dy < 4; ++dy)
#pragma unroll
        for (int dx = 0; dx < 3; ++dx)
            nbc[dy][dx] = xb[(h + dy) * WP + (w + dx)];

    // pixel-pair f32 vectors (cvt from f16), static indexing
    f32x2 prs[3][3][4];
#pragma unroll
    for (int ky = 0; ky < 3; ++ky)
#pragma unroll
        for (int kx = 0; kx < 3; ++kx) {
            uint2 cA = nbc[ky][kx], cB = nbc[ky + 1][kx];
            prs[ky][kx][0] = (f32x2){hlo(cA.x), hlo(cB.x)};
            prs[ky][kx][1] = (f32x2){hhi(cA.x), hhi(cB.x)};
            prs[ky][kx][2] = (f32x2){hlo(cA.y), hlo(cB.y)};
            prs[ky][kx][3] = (f32x2){hhi(cA.y), hhi(cB.y)};
        }

    // ---- offset conv: r-outer, local accumulator -> v_pk_fma_f32 ----
    f32x2 off2[18];
#pragma unroll
    for (int r = 0; r < 18; ++r) {
        float bias = b_p[r];                    // uniform -> s_load (input buf)
        f32x2 s = (f32x2){bias, bias};
#pragma unroll
        for (int ky = 0; ky < 3; ++ky)
#pragma unroll
            for (int kx = 0; kx < 3; ++kx) {
                const float* wr = w_p + r * 36 + ky * 3 + kx;  // uniform s_load
                s += wr[0] * prs[ky][kx][0] + wr[9] * prs[ky][kx][1]
                   + wr[18] * prs[ky][kx][2] + wr[27] * prs[ky][kx][3];
            }
        off2[r] = s;
    }

    float acc0[2] = {0.f, 0.f};
    float acc1[2] = {0.f, 0.f};
#pragma unroll
    for (int n = 0; n < 9; ++n) {
        int pny = n / 3 - 1;
        int pnx = n % 3 - 1;
        // packed coordinates for the pixel pair (f32 exact)
        f32x2 py2 = (f32x2){(float)(h + 1 + pny), (float)(h + 2 + pny)} + off2[n];
        f32x2 px2 = (float)(w + 1 + pnx) + off2[9 + n];
        f32x2 fy2 = {floorf(py2.x), floorf(py2.y)};
        f32x2 fx2 = {floorf(px2.x), floorf(px2.y)};
        f32x2 y0f = {fminf(fmaxf(fy2.x, 0.f), (float)(HP - 1)),
                     fminf(fmaxf(fy2.y, 0.f), (float)(HP - 1))};
        f32x2 y1f = {fminf(fmaxf(fy2.x + 1.f, 0.f), (float)(HP - 1)),
                     fminf(fmaxf(fy2.y + 1.f, 0.f), (float)(HP - 1))};
        f32x2 x0f = {fminf(fmaxf(fx2.x, 0.f), (float)(WP - 1)),
                     fminf(fmaxf(fx2.y, 0.f), (float)(WP - 1))};
        f32x2 x1f = {fminf(fmaxf(fx2.x + 1.f, 0.f), (float)(WP - 1)),
                     fminf(fmaxf(fx2.y + 1.f, 0.f), (float)(WP - 1))};
        f32x2 pyc = {fminf(fmaxf(py2.x, 0.f), (float)(HP - 1)),
                     fminf(fmaxf(py2.y, 0.f), (float)(HP - 1))};
        f32x2 pxc = {fminf(fmaxf(px2.x, 0.f), (float)(WP - 1)),
                     fminf(fmaxf(px2.y, 0.f), (float)(WP - 1))};
        f32x2 ay = 1.f + (y0f - pyc);
        f32x2 by = 1.f - (y1f - pyc);
        f32x2 ax = 1.f + (x0f - pxc);
        f32x2 bx = 1.f - (x1f - pxc);
        f32x2 glt = ay * ax, grb = by * bx, glb = ay * bx, grt = by * ax;

        // deform-conv weight packs (from uniform s_loads), shared over p
        unsigned wd00 = pku(w_dc[0 * 36 + 0 * 9 + n], w_dc[0 * 36 + 1 * 9 + n]);
        unsigned wd01 = pku(w_dc[0 * 36 + 2 * 9 + n], w_dc[0 * 36 + 3 * 9 + n]);
        unsigned wd10 = pku(w_dc[1 * 36 + 0 * 9 + n], w_dc[1 * 36 + 1 * 9 + n]);
        unsigned wd11 = pku(w_dc[1 * 36 + 2 * 9 + n], w_dc[1 * 36 + 3 * 9 + n]);

#pragma unroll
        for (int p = 0; p < 2; ++p) {           // p compile-time
            int y0 = (int)(p ? y0f.y : y0f.x);
            int y1 = (int)(p ? y1f.y : y1f.x);
            int x0 = (int)(p ? x0f.y : x0f.x);
            int x1 = (int)(p ? x1f.y : x1f.x);
            float g_lt = p ? glt.y : glt.x;
            float g_rb = p ? grb.y : grb.x;
            float g_lb = p ? glb.y : glb.x;
            float g_rt = p ? grt.y : grt.x;

            // paired-row 16B loads: cells (y,x0) and (y,x0+1)
            uint4a q0 = *(const uint4a*)(xbu + 2 * (y0 * WP + x0));
            uint4a q1 = *(const uint4a*)(xbu + 2 * (y1 * WP + x0));
            bool adj = (x1 > x0);               // x1 == x0+1 ? (else clamp: x1==x0)
            unsigned lt01 = q0.x, lt23 = q0.y;
            unsigned lb01 = adj ? q0.z : q0.x, lb23 = adj ? q0.w : q0.y;
            unsigned rt01 = q1.x, rt23 = q1.y;
            unsigned rb01 = adj ? q1.z : q1.x, rb23 = adj ? q1.w : q1.y;

            unsigned glt_h = pku(g_lt, g_lt);
            unsigned grb_h = pku(g_rb, g_rb);
            unsigned glb_h = pku(g_lb, g_lb);
            unsigned grt_h = pku(g_rt, g_rt);

            half2v h01 = b2h(glt_h) * b2h(lt01) + b2h(grb_h) * b2h(rb01)
                       + b2h(glb_h) * b2h(lb01) + b2h(grt_h) * b2h(rt01);
            half2v h23 = b2h(glt_h) * b2h(lt23) + b2h(grb_h) * b2h(rb23)
                       + b2h(glb_h) * b2h(lb23) + b2h(grt_h) * b2h(rt23);

            acc0[p] = dot2(h01, wd00, acc0[p]);
            acc0[p] = dot2(h23, wd01, acc0[p]);
            acc1[p] = dot2(h01, wd10, acc1[p]);
            acc1[p] = dot2(h23, wd11, acc1[p]);
        }
    }
#pragma unroll
    for (int p = 0; p < 2; ++p) {
        outb[(h + p) * WW + w] = acc0[p];
        outb[HH * WW + (h + p) * WW + w] = acc1[p];
    }
}

// ---------------------------------------------------------------------------
extern "C" void kernel_launch(void* const* d_in, const int* in_sizes, int n_in,
                              void* d_out, int out_size, void* d_ws, size_t ws_size,
                              hipStream_t stream) {
    const float* rgb  = (const float*)d_in[0];
    const float* sar  = (const float*)d_in[1];
    const float* w_fm = (const float*)d_in[2];
    const float* w_fs = (const float*)d_in[3];
    const float* w_p  = (const float*)d_in[4];
    const float* b_p  = (const float*)d_in[5];
    const float* w_dc = (const float*)d_in[6];
    float* out = (float*)d_out;

    // ws layout: fm [131072 f32] | xph [BB*HP*WP uint2 + 2 slack cells]
    float* ws = (float*)d_ws;
    float* fm = ws;
    uint2* xph = (uint2*)(ws + 131072);                // 8B aligned

    k_fm<<<BB * 128, 128, 0, stream>>>(rgb, w_fm, fm, xph);
    k_mat<<<BB * (HH / ROWS), 128, 0, stream>>>(rgb, sar, w_fs, fm, xph);
    k_deform<<<BB * (HH / 4), 256, 0, stream>>>(w_p, b_p, w_dc, xph, out);
}

// Round 13
// 67.212 us; speedup vs baseline: 1.0061x; 1.0061x over previous
//
#include <hip/hip_runtime.h>
#include <math.h>

typedef __attribute__((ext_vector_type(2))) _Float16 half2v;
typedef __attribute__((ext_vector_type(2))) float f32x2;
typedef __attribute__((ext_vector_type(4), aligned(8))) unsigned int uint4a;

#define BB 4
#define HH 2048
#define WW 128
#define HP (HH + 2)   // 2050
#define WP (WW + 2)   // 130
#define PP 128        // pooled size
#define ROWS 4

#define BORDER_PER_B (2 * WP + 2 * (HP - 2))   // 4356

__device__ __forceinline__ half2v b2h(unsigned u) { return __builtin_bit_cast(half2v, u); }
__device__ __forceinline__ unsigned pku(float a, float b) {
    return __builtin_bit_cast(unsigned, __builtin_amdgcn_cvt_pkrtz(a, b));
}
__device__ __forceinline__ float dot2(half2v a, unsigned wb, float c) {
    return __builtin_amdgcn_fdot2(a, b2h(wb), c, false);
}
__device__ __forceinline__ float hlo(unsigned u) { return (float)b2h(u).x; }
__device__ __forceinline__ float hhi(unsigned u) { return (float)b2h(u).y; }

// Shared XCD swizzle (R12-proven: k_deform FETCH 21->4.4MB). XCD k owns one
// contiguous 1024-row span of one batch in BOTH producer and consumer.
__device__ __forceinline__ void swz_map(int bid, int* b, int* h0) {
    int swz = (bid & 7) * 256 + (bid >> 3);
    *b = swz >> 9;
    *h0 = (swz & 511) * 4;
}

// ---------------------------------------------------------------------------
// Kernel 1: border-zero of xph (fused) + adaptive avg pool + 1x1 conv + sigmoid
// ---------------------------------------------------------------------------
__global__ void k_fm(const float* __restrict__ rgb, const float* __restrict__ w_fm,
                     float* __restrict__ fm, uint2* __restrict__ xph) {
    int j = threadIdx.x;              // 0..127
    int bi = blockIdx.x;              // b*128 + i
    int tid = bi * 128 + j;

    if (tid < BB * BORDER_PER_B) {
        int b = tid / BORDER_PER_B;
        int r = tid - b * BORDER_PER_B;
        int row, col;
        if (r < WP)          { row = 0;      col = r; }
        else if (r < 2 * WP) { row = HP - 1; col = r - WP; }
        else {
            int q = r - 2 * WP;
            row = 1 + (q >> 1);
            col = (q & 1) ? (WP - 1) : 0;
        }
        xph[((size_t)b * HP + row) * WP + col] = make_uint2(0u, 0u);
    }

    int b = bi >> 7, i = bi & 127;
    const float* r0 = rgb + ((size_t)(b * 2 + 0) * HH + (size_t)i * 16) * WW + j;
    const float* r1 = rgb + ((size_t)(b * 2 + 1) * HH + (size_t)i * 16) * WW + j;
    float s0 = 0.f, s1 = 0.f;
#pragma unroll
    for (int a = 0; a < 16; ++a) { s0 += r0[a * WW]; s1 += r1[a * WW]; }
    s0 *= (1.f / 16.f); s1 *= (1.f / 16.f);
    float f0 = w_fm[0] * s0 + w_fm[1] * s1;
    float f1 = w_fm[2] * s0 + w_fm[3] * s1;
    fm[((size_t)(b * 2 + 0) * PP + i) * PP + j] = 1.f / (1.f + expf(-f0));
    fm[((size_t)(b * 2 + 1) * PP + i) * PP + j] = 1.f / (1.f + expf(-f1));
}

// ---------------------------------------------------------------------------
// Kernel 2: mat = rgb @ fm + rgb (per b,c), fs = w_fs @ mat,
//           pack xph cell = f16x4 (sar0,sar1,fs0,fs1) as uint2 (8B).
// ---------------------------------------------------------------------------
__global__ __launch_bounds__(128) void k_mat(
        const float* __restrict__ rgb, const float* __restrict__ sar,
        const float* __restrict__ w_fs, const float* __restrict__ fm,
        uint2* __restrict__ xph) {
    int w = threadIdx.x;              // 0..127
    int b, h0;
    swz_map(blockIdx.x, &b, &h0);

    const float* rg0 = rgb + ((size_t)(b * 2 + 0) * HH + h0) * WW;  // uniform base
    const float* rg1 = rgb + ((size_t)(b * 2 + 1) * HH + h0) * WW;
    const float* fm0 = fm + (size_t)(b * 2 + 0) * PP * PP;
    const float* fm1 = fm + (size_t)(b * 2 + 1) * PP * PP;

    float acc0[ROWS], acc1[ROWS];
#pragma unroll
    for (int r = 0; r < ROWS; ++r) {                 // residual term
        acc0[r] = rg0[r * WW + w];
        acc1[r] = rg1[r * WW + w];
    }

#pragma unroll 4
    for (int k4 = 0; k4 < PP; k4 += 4) {
        float f0[4], f1[4];
#pragma unroll
        for (int t = 0; t < 4; ++t) {
            f0[t] = fm0[(size_t)(k4 + t) * PP + w];  // coalesced vector load
            f1[t] = fm1[(size_t)(k4 + t) * PP + w];
        }
#pragma unroll
        for (int r = 0; r < ROWS; ++r) {
            float4 a0 = *(const float4*)(rg0 + r * WW + k4);   // uniform -> s_load
            float4 a1 = *(const float4*)(rg1 + r * WW + k4);
            acc0[r] += a0.x * f0[0] + a0.y * f0[1] + a0.z * f0[2] + a0.w * f0[3];
            acc1[r] += a1.x * f1[0] + a1.y * f1[1] + a1.z * f1[2] + a1.w * f1[3];
        }
    }

    float wa = w_fs[0], wb = w_fs[1], wc = w_fs[2], wd = w_fs[3];
#pragma unroll
    for (int r = 0; r < ROWS; ++r) {
        float m0 = acc0[r], m1 = acc1[r];
        float fs0 = wa * m0 + wb * m1;
        float fs1 = wc * m0 + wd * m1;
        float s0 = sar[((size_t)(b * 2 + 0) * HH + (h0 + r)) * WW + w];
        float s1 = sar[((size_t)(b * 2 + 1) * HH + (h0 + r)) * WW + w];
        uint2 cell = make_uint2(pku(s0, s1), pku(fs0, fs1));
        xph[((size_t)b * HP + (h0 + r + 1)) * WP + (w + 1)] = cell;
    }
}

// ---------------------------------------------------------------------------
// Kernel 3: offset conv (f32 pk_fma) + deformable bilinear (f16) + dot2.
// 2 px/thread. Sampling loop restructured for MLP: groups of 3 n-points ->
// {compute 6 coord-sets, issue 12x16B loads, consume}. 12 loads in flight
// vs ~2 before (L2-hit ~200cy was the stall at VALUBusy 65%).
// All arrays statically indexed (full unroll). (256,2): 128-VGPR budget.
// ---------------------------------------------------------------------------
__global__ __launch_bounds__(256, 2) void k_deform(
        const float* __restrict__ w_p, const float* __restrict__ b_p,
        const float* __restrict__ w_dc, const uint2* __restrict__ xph,
        float* __restrict__ out) {
    int b, h0;
    swz_map(blockIdx.x, &b, &h0);
    int tid = threadIdx.x;
    int w = tid & 127;
    int h = h0 + ((tid >> 7) << 1);             // this thread: rows h, h+1

    const uint2* xb = xph + (size_t)b * HP * WP;          // SGPR base
    const unsigned* xbu = (const unsigned*)xb;
    float* outb = out + (size_t)(b * 2) * HH * WW;        // SGPR base

    // 4 rows x 3 cols f16 neighborhood (8B cells)
    uint2 nbc[4][3];
#pragma unroll
    for (int dy = 0; dy < 4; ++dy)
#pragma unroll
        for (int dx = 0; dx < 3; ++dx)
            nbc[dy][dx] = xb[(h + dy) * WP + (w + dx)];

    // pixel-pair f32 vectors (cvt from f16), static indexing
    f32x2 prs[3][3][4];
#pragma unroll
    for (int ky = 0; ky < 3; ++ky)
#pragma unroll
        for (int kx = 0; kx < 3; ++kx) {
            uint2 cA = nbc[ky][kx], cB = nbc[ky + 1][kx];
            prs[ky][kx][0] = (f32x2){hlo(cA.x), hlo(cB.x)};
            prs[ky][kx][1] = (f32x2){hhi(cA.x), hhi(cB.x)};
            prs[ky][kx][2] = (f32x2){hlo(cA.y), hlo(cB.y)};
            prs[ky][kx][3] = (f32x2){hhi(cA.y), hhi(cB.y)};
        }

    // ---- offset conv: r-outer, local accumulator -> v_pk_fma_f32 ----
    f32x2 off2[18];
#pragma unroll
    for (int r = 0; r < 18; ++r) {
        float bias = b_p[r];                    // uniform -> s_load (input buf)
        f32x2 s = (f32x2){bias, bias};
#pragma unroll
        for (int ky = 0; ky < 3; ++ky)
#pragma unroll
            for (int kx = 0; kx < 3; ++kx) {
                const float* wr = w_p + r * 36 + ky * 3 + kx;  // uniform s_load
                s += wr[0] * prs[ky][kx][0] + wr[9] * prs[ky][kx][1]
                   + wr[18] * prs[ky][kx][2] + wr[27] * prs[ky][kx][3];
            }
        off2[r] = s;
    }

    float acc0[2] = {0.f, 0.f};
    float acc1[2] = {0.f, 0.f};

#pragma unroll
    for (int g = 0; g < 3; ++g) {               // groups of 3 sampling points
        unsigned hg[3][2][4];                   // g-weight f16 splats
        bool adj[3][2];
        uint4a q0[3][2], q1[3][2];              // paired-row 16B loads

        // ---- phase 1+2: coords, g-weights, issue all 12 loads ----
#pragma unroll
        for (int j = 0; j < 3; ++j) {
            int n = g * 3 + j;
            int pny = n / 3 - 1;
            int pnx = n % 3 - 1;
            f32x2 py2 = (f32x2){(float)(h + 1 + pny), (float)(h + 2 + pny)} + off2[n];
            f32x2 px2 = (float)(w + 1 + pnx) + off2[9 + n];
            f32x2 fy2 = {floorf(py2.x), floorf(py2.y)};
            f32x2 fx2 = {floorf(px2.x), floorf(px2.y)};
            f32x2 y0f = {fminf(fmaxf(fy2.x, 0.f), (float)(HP - 1)),
                         fminf(fmaxf(fy2.y, 0.f), (float)(HP - 1))};
            f32x2 y1f = {fminf(fmaxf(fy2.x + 1.f, 0.f), (float)(HP - 1)),
                         fminf(fmaxf(fy2.y + 1.f, 0.f), (float)(HP - 1))};
            f32x2 x0f = {fminf(fmaxf(fx2.x, 0.f), (float)(WP - 1)),
                         fminf(fmaxf(fx2.y, 0.f), (float)(WP - 1))};
            f32x2 x1f = {fminf(fmaxf(fx2.x + 1.f, 0.f), (float)(WP - 1)),
                         fminf(fmaxf(fx2.y + 1.f, 0.f), (float)(WP - 1))};
            f32x2 pyc = {fminf(fmaxf(py2.x, 0.f), (float)(HP - 1)),
                         fminf(fmaxf(py2.y, 0.f), (float)(HP - 1))};
            f32x2 pxc = {fminf(fmaxf(px2.x, 0.f), (float)(WP - 1)),
                         fminf(fmaxf(px2.y, 0.f), (float)(WP - 1))};
            f32x2 ay = 1.f + (y0f - pyc);
            f32x2 by = 1.f - (y1f - pyc);
            f32x2 ax = 1.f + (x0f - pxc);
            f32x2 bx = 1.f - (x1f - pxc);
            f32x2 glt = ay * ax, grb = by * bx, glb = ay * bx, grt = by * ax;

#pragma unroll
            for (int p = 0; p < 2; ++p) {       // p compile-time
                int y0 = (int)(p ? y0f.y : y0f.x);
                int y1 = (int)(p ? y1f.y : y1f.x);
                int x0 = (int)(p ? x0f.y : x0f.x);
                int x1 = (int)(p ? x1f.y : x1f.x);
                float g_lt = p ? glt.y : glt.x;
                float g_rb = p ? grb.y : grb.x;
                float g_lb = p ? glb.y : glb.x;
                float g_rt = p ? grt.y : grt.x;
                hg[j][p][0] = pku(g_lt, g_lt);
                hg[j][p][1] = pku(g_rb, g_rb);
                hg[j][p][2] = pku(g_lb, g_lb);
                hg[j][p][3] = pku(g_rt, g_rt);
                adj[j][p] = (x1 > x0);
                q0[j][p] = *(const uint4a*)(xbu + 2 * (y0 * WP + x0));
                q1[j][p] = *(const uint4a*)(xbu + 2 * (y1 * WP + x0));
            }
        }

        // ---- phase 3: consume (select, f16 interp, dot2 combine) ----
#pragma unroll
        for (int j = 0; j < 3; ++j) {
            int n = g * 3 + j;
            unsigned wd00 = pku(w_dc[0 * 36 + 0 * 9 + n], w_dc[0 * 36 + 1 * 9 + n]);
            unsigned wd01 = pku(w_dc[0 * 36 + 2 * 9 + n], w_dc[0 * 36 + 3 * 9 + n]);
            unsigned wd10 = pku(w_dc[1 * 36 + 0 * 9 + n], w_dc[1 * 36 + 1 * 9 + n]);
            unsigned wd11 = pku(w_dc[1 * 36 + 2 * 9 + n], w_dc[1 * 36 + 3 * 9 + n]);
#pragma unroll
            for (int p = 0; p < 2; ++p) {
                uint4a a = q0[j][p], c = q1[j][p];
                bool ad = adj[j][p];
                unsigned lt01 = a.x, lt23 = a.y;
                unsigned lb01 = ad ? a.z : a.x, lb23 = ad ? a.w : a.y;
                unsigned rt01 = c.x, rt23 = c.y;
                unsigned rb01 = ad ? c.z : c.x, rb23 = ad ? c.w : c.y;

                half2v h01 = b2h(hg[j][p][0]) * b2h(lt01) + b2h(hg[j][p][1]) * b2h(rb01)
                           + b2h(hg[j][p][2]) * b2h(lb01) + b2h(hg[j][p][3]) * b2h(rt01);
                half2v h23 = b2h(hg[j][p][0]) * b2h(lt23) + b2h(hg[j][p][1]) * b2h(rb23)
                           + b2h(hg[j][p][2]) * b2h(lb23) + b2h(hg[j][p][3]) * b2h(rt23);

                acc0[p] = dot2(h01, wd00, acc0[p]);
                acc0[p] = dot2(h23, wd01, acc0[p]);
                acc1[p] = dot2(h01, wd10, acc1[p]);
                acc1[p] = dot2(h23, wd11, acc1[p]);
            }
        }
    }
#pragma unroll
    for (int p = 0; p < 2; ++p) {
        outb[(h + p) * WW + w] = acc0[p];
        outb[HH * WW + (h + p) * WW + w] = acc1[p];
    }
}

// ---------------------------------------------------------------------------
extern "C" void kernel_launch(void* const* d_in, const int* in_sizes, int n_in,
                              void* d_out, int out_size, void* d_ws, size_t ws_size,
                              hipStream_t stream) {
    const float* rgb  = (const float*)d_in[0];
    const float* sar  = (const float*)d_in[1];
    const float* w_fm = (const float*)d_in[2];
    const float* w_fs = (const float*)d_in[3];
    const float* w_p  = (const float*)d_in[4];
    const float* b_p  = (const float*)d_in[5];
    const float* w_dc = (const float*)d_in[6];
    float* out = (float*)d_out;

    // ws layout: fm [131072 f32] | xph [BB*HP*WP uint2 + 2 slack cells]
    float* ws = (float*)d_ws;
    float* fm = ws;
    uint2* xph = (uint2*)(ws + 131072);                // 8B aligned

    k_fm<<<BB * 128, 128, 0, stream>>>(rgb, w_fm, fm, xph);
    k_mat<<<BB * (HH / ROWS), 128, 0, stream>>>(rgb, sar, w_fs, fm, xph);
    k_deform<<<BB * (HH / 4), 256, 0, stream>>>(w_p, b_p, w_dc, xph, out);
}

// Round 14
// 58.428 us; speedup vs baseline: 1.1573x; 1.1503x over previous
//
#include <hip/hip_runtime.h>
#include <math.h>

typedef __attribute__((ext_vector_type(2))) _Float16 half2v;
typedef __attribute__((ext_vector_type(2))) float f32x2;
typedef __attribute__((ext_vector_type(4), aligned(8))) unsigned int uint4a;

#define BB 4
#define HH 2048
#define WW 128
#define HP (HH + 2)   // 2050
#define WP (WW + 2)   // 130
#define PP 128        // pooled size
#define ROWS 4

#define BORDER_PER_B (2 * WP + 2 * (HP - 2))   // 4356

__device__ __forceinline__ half2v b2h(unsigned u) { return __builtin_bit_cast(half2v, u); }
__device__ __forceinline__ unsigned pku(float a, float b) {
    return __builtin_bit_cast(unsigned, __builtin_amdgcn_cvt_pkrtz(a, b));
}
__device__ __forceinline__ float dot2(half2v a, unsigned wb, float c) {
    return __builtin_amdgcn_fdot2(a, b2h(wb), c, false);
}
__device__ __forceinline__ float hlo(unsigned u) { return (float)b2h(u).x; }
__device__ __forceinline__ float hhi(unsigned u) { return (float)b2h(u).y; }

// XCD co-location (R12-proven: FETCH 21->4.4MB). XCD k = bid%8 (round-robin
// dispatch) owns one contiguous 1024-row span of one batch in BOTH producer
// and consumer, regardless of block granularity:
//   k_mat:    2048 blocks x 4 rows: swz=(bid&7)*256+(bid>>3); b=swz>>9; h0=(swz&511)*4
//   k_deform: 4096 blocks x 2 rows: swz=(bid&7)*512+(bid>>3); b=swz>>10; h0=(swz&1023)*2
// Both give XCD k -> batch k/2, rows [(k%2)*1024, +1023].

// ---------------------------------------------------------------------------
// Kernel 1: border-zero of xph (fused) + adaptive avg pool + 1x1 conv +
// sigmoid. PAIR-ROW version: thread (b,t,j) computes fm rows 2t,2t+1 at col j
// and stores them as one float2 -> fmp[(b*2+c)*64+t][j] (k-pair layout for
// k_mat's v_pk_fma_f32 inner loop). All f32 exact.
// ---------------------------------------------------------------------------
__global__ void k_fm(const float* __restrict__ rgb, const float* __restrict__ w_fm,
                     float2* __restrict__ fmp, uint2* __restrict__ xph) {
    int j = threadIdx.x;              // 0..127
    int bi = blockIdx.x;              // b*64 + t
    int tid = bi * 128 + j;

    if (tid < BB * BORDER_PER_B) {    // 17424 <= 32768 threads
        int b = tid / BORDER_PER_B;
        int r = tid - b * BORDER_PER_B;
        int row, col;
        if (r < WP)          { row = 0;      col = r; }
        else if (r < 2 * WP) { row = HP - 1; col = r - WP; }
        else {
            int q = r - 2 * WP;
            row = 1 + (q >> 1);
            col = (q & 1) ? (WP - 1) : 0;
        }
        xph[((size_t)b * HP + row) * WP + col] = make_uint2(0u, 0u);
    }

    int b = bi >> 6, t = bi & 63;     // fm rows 2t, 2t+1 <- rgb rows 32t..32t+31
    const float* r0 = rgb + ((size_t)(b * 2 + 0) * HH + (size_t)t * 32) * WW + j;
    const float* r1 = rgb + ((size_t)(b * 2 + 1) * HH + (size_t)t * 32) * WW + j;
    float sA0 = 0.f, sA1 = 0.f, sB0 = 0.f, sB1 = 0.f;
#pragma unroll
    for (int a = 0; a < 16; ++a) { sA0 += r0[a * WW]; sA1 += r1[a * WW]; }
#pragma unroll
    for (int a = 16; a < 32; ++a) { sB0 += r0[a * WW]; sB1 += r1[a * WW]; }
    sA0 *= (1.f / 16.f); sA1 *= (1.f / 16.f);
    sB0 *= (1.f / 16.f); sB1 *= (1.f / 16.f);
    float fA0 = w_fm[0] * sA0 + w_fm[1] * sA1;   // out ch0, row 2t
    float fA1 = w_fm[2] * sA0 + w_fm[3] * sA1;   // out ch1, row 2t
    float fB0 = w_fm[0] * sB0 + w_fm[1] * sB1;   // out ch0, row 2t+1
    float fB1 = w_fm[2] * sB0 + w_fm[3] * sB1;   // out ch1, row 2t+1
    float gA0 = 1.f / (1.f + expf(-fA0)), gB0 = 1.f / (1.f + expf(-fB0));
    float gA1 = 1.f / (1.f + expf(-fA1)), gB1 = 1.f / (1.f + expf(-fB1));
    fmp[((size_t)(b * 2 + 0) * 64 + t) * PP + j] = make_float2(gA0, gB0);
    fmp[((size_t)(b * 2 + 1) * 64 + t) * PP + j] = make_float2(gA1, gB1);
}

// ---------------------------------------------------------------------------
// Kernel 2: mat = rgb @ fm + rgb (per b,c), fs = w_fs @ mat, xph = f16 cells.
// fm in k-pair float2 layout -> inner loop is 2 dwordx2 loads + 8 v_pk_fma_f32
// per k-pair (halved VALU vs scalar fmac). A-side = uniform s_load f32 pairs
// straight from the immutable rgb input (exact).
// ---------------------------------------------------------------------------
__global__ __launch_bounds__(128) void k_mat(
        const float* __restrict__ rgb, const float* __restrict__ sar,
        const float* __restrict__ w_fs, const float2* __restrict__ fmp,
        uint2* __restrict__ xph) {
    int w = threadIdx.x;              // 0..127
    int bid = blockIdx.x;
    int swz = (bid & 7) * 256 + (bid >> 3);
    int b = swz >> 9;
    int h0 = (swz & 511) * 4;

    const float* rg0 = rgb + ((size_t)(b * 2 + 0) * HH + h0) * WW;  // uniform base
    const float* rg1 = rgb + ((size_t)(b * 2 + 1) * HH + h0) * WW;
    const float2* fp0 = fmp + (size_t)(b * 2 + 0) * 64 * PP;
    const float2* fp1 = fmp + (size_t)(b * 2 + 1) * 64 * PP;

    f32x2 av0[ROWS], av1[ROWS];
#pragma unroll
    for (int r = 0; r < ROWS; ++r) {                 // residual term in lane .x
        av0[r] = (f32x2){rg0[r * WW + w], 0.f};
        av1[r] = (f32x2){rg1[r * WW + w], 0.f};
    }

#pragma unroll 4
    for (int t = 0; t < 64; ++t) {                   // k-pair (2t, 2t+1)
        float2 f0 = fp0[(size_t)t * PP + w];         // coalesced dwordx2
        float2 f1 = fp1[(size_t)t * PP + w];
        f32x2 fv0 = {f0.x, f0.y};
        f32x2 fv1 = {f1.x, f1.y};
#pragma unroll
        for (int r = 0; r < ROWS; ++r) {
            f32x2 a0 = *(const f32x2*)(rg0 + r * WW + 2 * t);   // uniform s_load
            f32x2 a1 = *(const f32x2*)(rg1 + r * WW + 2 * t);
            av0[r] += a0 * fv0;                      // v_pk_fma_f32
            av1[r] += a1 * fv1;
        }
    }

    float wa = w_fs[0], wb = w_fs[1], wc = w_fs[2], wd = w_fs[3];
#pragma unroll
    for (int r = 0; r < ROWS; ++r) {
        float m0 = av0[r].x + av0[r].y;
        float m1 = av1[r].x + av1[r].y;
        float fs0 = wa * m0 + wb * m1;
        float fs1 = wc * m0 + wd * m1;
        float s0 = sar[((size_t)(b * 2 + 0) * HH + (h0 + r)) * WW + w];
        float s1 = sar[((size_t)(b * 2 + 1) * HH + (h0 + r)) * WW + w];
        uint2 cell = make_uint2(pku(s0, s1), pku(fs0, fs1));
        xph[((size_t)b * HP + (h0 + r + 1)) * WP + (w + 1)] = cell;
    }
}

// ---------------------------------------------------------------------------
// Kernel 3: offset conv (f32 pk_fma) + deformable bilinear (f16) + dot2.
// 2 px/thread, 128-THREAD BLOCKS (4096 blocks): occupancy experiment — finer
// dispatch granularity vs R13's 256-thr blocks (resident ~2.4/8 blocks/CU).
// Body identical to R13 (groups-of-3 MLP batching).
// ---------------------------------------------------------------------------
__global__ __launch_bounds__(128) void k_deform(
        const float* __restrict__ w_p, const float* __restrict__ b_p,
        const float* __restrict__ w_dc, const uint2* __restrict__ xph,
        float* __restrict__ out) {
    int bid = blockIdx.x;
    int swz = (bid & 7) * 512 + (bid >> 3);
    int b = swz >> 10;
    int h = (swz & 1023) * 2;                   // this block: rows h, h+1
    int w = threadIdx.x;                        // 0..127

    const uint2* xb = xph + (size_t)b * HP * WP;          // SGPR base
    const unsigned* xbu = (const unsigned*)xb;
    float* outb = out + (size_t)(b * 2) * HH * WW;        // SGPR base

    // 4 rows x 3 cols f16 neighborhood (8B cells)
    uint2 nbc[4][3];
#pragma unroll
    for (int dy = 0; dy < 4; ++dy)
#pragma unroll
        for (int dx = 0; dx < 3; ++dx)
            nbc[dy][dx] = xb[(h + dy) * WP + (w + dx)];

    // pixel-pair f32 vectors (cvt from f16), static indexing
    f32x2 prs[3][3][4];
#pragma unroll
    for (int ky = 0; ky < 3; ++ky)
#pragma unroll
        for (int kx = 0; kx < 3; ++kx) {
            uint2 cA = nbc[ky][kx], cB = nbc[ky + 1][kx];
            prs[ky][kx][0] = (f32x2){hlo(cA.x), hlo(cB.x)};
            prs[ky][kx][1] = (f32x2){hhi(cA.x), hhi(cB.x)};
            prs[ky][kx][2] = (f32x2){hlo(cA.y), hlo(cB.y)};
            prs[ky][kx][3] = (f32x2){hhi(cA.y), hhi(cB.y)};
        }

    // ---- offset conv: r-outer, local accumulator -> v_pk_fma_f32 ----
    f32x2 off2[18];
#pragma unroll
    for (int r = 0; r < 18; ++r) {
        float bias = b_p[r];                    // uniform -> s_load (input buf)
        f32x2 s = (f32x2){bias, bias};
#pragma unroll
        for (int ky = 0; ky < 3; ++ky)
#pragma unroll
            for (int kx = 0; kx < 3; ++kx) {
                const float* wr = w_p + r * 36 + ky * 3 + kx;  // uniform s_load
                s += wr[0] * prs[ky][kx][0] + wr[9] * prs[ky][kx][1]
                   + wr[18] * prs[ky][kx][2] + wr[27] * prs[ky][kx][3];
            }
        off2[r] = s;
    }

    float acc0[2] = {0.f, 0.f};
    float acc1[2] = {0.f, 0.f};

#pragma unroll
    for (int g = 0; g < 3; ++g) {               // groups of 3 sampling points
        unsigned hg[3][2][4];                   // g-weight f16 splats
        bool adj[3][2];
        uint4a q0[3][2], q1[3][2];              // paired-row 16B loads

        // ---- phase 1+2: coords, g-weights, issue all 12 loads ----
#pragma unroll
        for (int j = 0; j < 3; ++j) {
            int n = g * 3 + j;
            int pny = n / 3 - 1;
            int pnx = n % 3 - 1;
            f32x2 py2 = (f32x2){(float)(h + 1 + pny), (float)(h + 2 + pny)} + off2[n];
            f32x2 px2 = (float)(w + 1 + pnx) + off2[9 + n];
            f32x2 fy2 = {floorf(py2.x), floorf(py2.y)};
            f32x2 fx2 = {floorf(px2.x), floorf(px2.y)};
            f32x2 y0f = {fminf(fmaxf(fy2.x, 0.f), (float)(HP - 1)),
                         fminf(fmaxf(fy2.y, 0.f), (float)(HP - 1))};
            f32x2 y1f = {fminf(fmaxf(fy2.x + 1.f, 0.f), (float)(HP - 1)),
                         fminf(fmaxf(fy2.y + 1.f, 0.f), (float)(HP - 1))};
            f32x2 x0f = {fminf(fmaxf(fx2.x, 0.f), (float)(WP - 1)),
                         fminf(fmaxf(fx2.y, 0.f), (float)(WP - 1))};
            f32x2 x1f = {fminf(fmaxf(fx2.x + 1.f, 0.f), (float)(WP - 1)),
                         fminf(fmaxf(fx2.y + 1.f, 0.f), (float)(WP - 1))};
            f32x2 pyc = {fminf(fmaxf(py2.x, 0.f), (float)(HP - 1)),
                         fminf(fmaxf(py2.y, 0.f), (float)(HP - 1))};
            f32x2 pxc = {fminf(fmaxf(px2.x, 0.f), (float)(WP - 1)),
                         fminf(fmaxf(px2.y, 0.f), (float)(WP - 1))};
            f32x2 ay = 1.f + (y0f - pyc);
            f32x2 by = 1.f - (y1f - pyc);
            f32x2 ax = 1.f + (x0f - pxc);
            f32x2 bx = 1.f - (x1f - pxc);
            f32x2 glt = ay * ax, grb = by * bx, glb = ay * bx, grt = by * ax;

#pragma unroll
            for (int p = 0; p < 2; ++p) {       // p compile-time
                int y0 = (int)(p ? y0f.y : y0f.x);
                int y1 = (int)(p ? y1f.y : y1f.x);
                int x0 = (int)(p ? x0f.y : x0f.x);
                int x1 = (int)(p ? x1f.y : x1f.x);
                float g_lt = p ? glt.y : glt.x;
                float g_rb = p ? grb.y : grb.x;
                float g_lb = p ? glb.y : glb.x;
                float g_rt = p ? grt.y : grt.x;
                hg[j][p][0] = pku(g_lt, g_lt);
                hg[j][p][1] = pku(g_rb, g_rb);
                hg[j][p][2] = pku(g_lb, g_lb);
                hg[j][p][3] = pku(g_rt, g_rt);
                adj[j][p] = (x1 > x0);
                q0[j][p] = *(const uint4a*)(xbu + 2 * (y0 * WP + x0));
                q1[j][p] = *(const uint4a*)(xbu + 2 * (y1 * WP + x0));
            }
        }

        // ---- phase 3: consume (select, f16 interp, dot2 combine) ----
#pragma unroll
        for (int j = 0; j < 3; ++j) {
            int n = g * 3 + j;
            unsigned wd00 = pku(w_dc[0 * 36 + 0 * 9 + n], w_dc[0 * 36 + 1 * 9 + n]);
            unsigned wd01 = pku(w_dc[0 * 36 + 2 * 9 + n], w_dc[0 * 36 + 3 * 9 + n]);
            unsigned wd10 = pku(w_dc[1 * 36 + 0 * 9 + n], w_dc[1 * 36 + 1 * 9 + n]);
            unsigned wd11 = pku(w_dc[1 * 36 + 2 * 9 + n], w_dc[1 * 36 + 3 * 9 + n]);
#pragma unroll
            for (int p = 0; p < 2; ++p) {
                uint4a a = q0[j][p], c = q1[j][p];
                bool ad = adj[j][p];
                unsigned lt01 = a.x, lt23 = a.y;
                unsigned lb01 = ad ? a.z : a.x, lb23 = ad ? a.w : a.y;
                unsigned rt01 = c.x, rt23 = c.y;
                unsigned rb01 = ad ? c.z : c.x, rb23 = ad ? c.w : c.y;

                half2v h01 = b2h(hg[j][p][0]) * b2h(lt01) + b2h(hg[j][p][1]) * b2h(rb01)
                           + b2h(hg[j][p][2]) * b2h(lb01) + b2h(hg[j][p][3]) * b2h(rt01);
                half2v h23 = b2h(hg[j][p][0]) * b2h(lt23) + b2h(hg[j][p][1]) * b2h(rb23)
                           + b2h(hg[j][p][2]) * b2h(lb23) + b2h(hg[j][p][3]) * b2h(rt23);

                acc0[p] = dot2(h01, wd00, acc0[p]);
                acc0[p] = dot2(h23, wd01, acc0[p]);
                acc1[p] = dot2(h01, wd10, acc1[p]);
                acc1[p] = dot2(h23, wd11, acc1[p]);
            }
        }
    }
#pragma unroll
    for (int p = 0; p < 2; ++p) {
        outb[(h + p) * WW + w] = acc0[p];
        outb[HH * WW + (h + p) * WW + w] = acc1[p];
    }
}

// ---------------------------------------------------------------------------
extern "C" void kernel_launch(void* const* d_in, const int* in_sizes, int n_in,
                              void* d_out, int out_size, void* d_ws, size_t ws_size,
                              hipStream_t stream) {
    const float* rgb  = (const float*)d_in[0];
    const float* sar  = (const float*)d_in[1];
    const float* w_fm = (const float*)d_in[2];
    const float* w_fs = (const float*)d_in[3];
    const float* w_p  = (const float*)d_in[4];
    const float* b_p  = (const float*)d_in[5];
    const float* w_dc = (const float*)d_in[6];
    float* out = (float*)d_out;

    // ws layout: fmp [65536 float2 = 131072 f32] | xph [BB*HP*WP uint2 + slack]
    float* ws = (float*)d_ws;
    float2* fmp = (float2*)ws;
    uint2* xph = (uint2*)(ws + 131072);                // 8B aligned

    k_fm<<<BB * 64, 128, 0, stream>>>(rgb, w_fm, fmp, xph);
    k_mat<<<BB * (HH / ROWS), 128, 0, stream>>>(rgb, sar, w_fs, fmp, xph);
    k_deform<<<BB * (HH / 2), 128, 0, stream>>>(w_p, b_p, w_dc, xph, out);
}

// Round 15
// 56.015 us; speedup vs baseline: 1.2072x; 1.0431x over previous
//
#include <hip/hip_runtime.h>
#include <math.h>

typedef __attribute__((ext_vector_type(2))) _Float16 half2v;
typedef __attribute__((ext_vector_type(2))) float f32x2;
typedef __attribute__((ext_vector_type(4), aligned(8))) unsigned int uint4a;

#define BB 4
#define HH 2048
#define WW 128
#define HP (HH + 2)   // 2050
#define WP (WW + 2)   // 130
#define PP 128        // pooled size
#define MROWS 8       // k_mat rows/block (halves fm L2 re-read vs 4)

#define BORDER_PER_B (2 * WP + 2 * (HP - 2))   // 4356

__device__ __forceinline__ half2v b2h(unsigned u) { return __builtin_bit_cast(half2v, u); }
__device__ __forceinline__ unsigned pku(float a, float b) {
    return __builtin_bit_cast(unsigned, __builtin_amdgcn_cvt_pkrtz(a, b));
}
__device__ __forceinline__ float dot2(half2v a, unsigned wb, float c) {
    return __builtin_amdgcn_fdot2(a, b2h(wb), c, false);
}
__device__ __forceinline__ float hlo(unsigned u) { return (float)b2h(u).x; }
__device__ __forceinline__ float hhi(unsigned u) { return (float)b2h(u).y; }

// XCD co-location (R12-proven: FETCH 21->4.4MB; R14 granularity win).
// XCD k = bid%8 (round-robin) owns batch k/2, rows [(k&1)*1024, +1024) in
// BOTH producer and consumer:
//   k_mat:    1024 blocks x 8 rows: swz=(bid&7)*128+(bid>>3); b=swz>>8; h0=(swz&255)*8
//   k_deform: 4096 blocks x 2 rows: swz=(bid&7)*512+(bid>>3); b=swz>>10; h=(swz&1023)*2

// ---------------------------------------------------------------------------
// Kernel 1: border-zero of xph (fused) + adaptive avg pool + 1x1 conv +
// sigmoid. Pair-row: thread (b,t,j) computes fm rows 2t,2t+1 at col j, stored
// as float2 k-pair -> fmp[(b*2+c)*64+t][j] (feeds k_mat's v_pk_fma_f32).
// ---------------------------------------------------------------------------
__global__ void k_fm(const float* __restrict__ rgb, const float* __restrict__ w_fm,
                     float2* __restrict__ fmp, uint2* __restrict__ xph) {
    int j = threadIdx.x;              // 0..127
    int bi = blockIdx.x;              // b*64 + t
    int tid = bi * 128 + j;

    if (tid < BB * BORDER_PER_B) {    // 17424 <= 32768 threads
        int b = tid / BORDER_PER_B;
        int r = tid - b * BORDER_PER_B;
        int row, col;
        if (r < WP)          { row = 0;      col = r; }
        else if (r < 2 * WP) { row = HP - 1; col = r - WP; }
        else {
            int q = r - 2 * WP;
            row = 1 + (q >> 1);
            col = (q & 1) ? (WP - 1) : 0;
        }
        xph[((size_t)b * HP + row) * WP + col] = make_uint2(0u, 0u);
    }

    int b = bi >> 6, t = bi & 63;     // fm rows 2t, 2t+1 <- rgb rows 32t..32t+31
    const float* r0 = rgb + ((size_t)(b * 2 + 0) * HH + (size_t)t * 32) * WW + j;
    const float* r1 = rgb + ((size_t)(b * 2 + 1) * HH + (size_t)t * 32) * WW + j;
    float sA0 = 0.f, sA1 = 0.f, sB0 = 0.f, sB1 = 0.f;
#pragma unroll
    for (int a = 0; a < 16; ++a) { sA0 += r0[a * WW]; sA1 += r1[a * WW]; }
#pragma unroll
    for (int a = 16; a < 32; ++a) { sB0 += r0[a * WW]; sB1 += r1[a * WW]; }
    sA0 *= (1.f / 16.f); sA1 *= (1.f / 16.f);
    sB0 *= (1.f / 16.f); sB1 *= (1.f / 16.f);
    float fA0 = w_fm[0] * sA0 + w_fm[1] * sA1;
    float fA1 = w_fm[2] * sA0 + w_fm[3] * sA1;
    float fB0 = w_fm[0] * sB0 + w_fm[1] * sB1;
    float fB1 = w_fm[2] * sB0 + w_fm[3] * sB1;
    float gA0 = 1.f / (1.f + expf(-fA0)), gB0 = 1.f / (1.f + expf(-fB0));
    float gA1 = 1.f / (1.f + expf(-fA1)), gB1 = 1.f / (1.f + expf(-fB1));
    fmp[((size_t)(b * 2 + 0) * 64 + t) * PP + j] = make_float2(gA0, gB0);
    fmp[((size_t)(b * 2 + 1) * 64 + t) * PP + j] = make_float2(gA1, gB1);
}

// ---------------------------------------------------------------------------
// Kernel 2: mat = rgb @ fm + rgb (per b,c), fs = w_fs @ mat, xph = f16 cells.
// MROWS=8: fm panel re-read halved (268->134MB L2). fm in k-pair float2
// layout -> v_pk_fma_f32 inner loop; A-side uniform s_load f32 pairs (exact).
// ---------------------------------------------------------------------------
__global__ __launch_bounds__(128) void k_mat(
        const float* __restrict__ rgb, const float* __restrict__ sar,
        const float* __restrict__ w_fs, const float2* __restrict__ fmp,
        uint2* __restrict__ xph) {
    int w = threadIdx.x;              // 0..127
    int bid = blockIdx.x;             // 0..1023
    int swz = (bid & 7) * 128 + (bid >> 3);
    int b = swz >> 8;
    int h0 = (swz & 255) * 8;

    const float* rg0 = rgb + ((size_t)(b * 2 + 0) * HH + h0) * WW;  // uniform base
    const float* rg1 = rgb + ((size_t)(b * 2 + 1) * HH + h0) * WW;
    const float2* fp0 = fmp + (size_t)(b * 2 + 0) * 64 * PP;
    const float2* fp1 = fmp + (size_t)(b * 2 + 1) * 64 * PP;

    f32x2 av0[MROWS], av1[MROWS];
#pragma unroll
    for (int r = 0; r < MROWS; ++r) {                // residual term in lane .x
        av0[r] = (f32x2){rg0[r * WW + w], 0.f};
        av1[r] = (f32x2){rg1[r * WW + w], 0.f};
    }

#pragma unroll 4
    for (int t = 0; t < 64; ++t) {                   // k-pair (2t, 2t+1)
        float2 f0 = fp0[(size_t)t * PP + w];         // coalesced dwordx2
        float2 f1 = fp1[(size_t)t * PP + w];
        f32x2 fv0 = {f0.x, f0.y};
        f32x2 fv1 = {f1.x, f1.y};
#pragma unroll
        for (int r = 0; r < MROWS; ++r) {
            f32x2 a0 = *(const f32x2*)(rg0 + r * WW + 2 * t);   // uniform s_load
            f32x2 a1 = *(const f32x2*)(rg1 + r * WW + 2 * t);
            av0[r] += a0 * fv0;                      // v_pk_fma_f32
            av1[r] += a1 * fv1;
        }
    }

    float wa = w_fs[0], wb = w_fs[1], wc = w_fs[2], wd = w_fs[3];
#pragma unroll
    for (int r = 0; r < MROWS; ++r) {
        float m0 = av0[r].x + av0[r].y;
        float m1 = av1[r].x + av1[r].y;
        float fs0 = wa * m0 + wb * m1;
        float fs1 = wc * m0 + wd * m1;
        float s0 = sar[((size_t)(b * 2 + 0) * HH + (h0 + r)) * WW + w];
        float s1 = sar[((size_t)(b * 2 + 1) * HH + (h0 + r)) * WW + w];
        uint2 cell = make_uint2(pku(s0, s1), pku(fs0, fs1));
        xph[((size_t)b * HP + (h0 + r + 1)) * WP + (w + 1)] = cell;
    }
}

// ---------------------------------------------------------------------------
// Kernel 3: offset conv (f32 pk_fma) + deformable bilinear (f16) + dot2.
// 2 px/thread, 128-thr blocks (R14-proven best). Body frozen.
// ---------------------------------------------------------------------------
__global__ __launch_bounds__(128) void k_deform(
        const float* __restrict__ w_p, const float* __restrict__ b_p,
        const float* __restrict__ w_dc, const uint2* __restrict__ xph,
        float* __restrict__ out) {
    int bid = blockIdx.x;
    int swz = (bid & 7) * 512 + (bid >> 3);
    int b = swz >> 10;
    int h = (swz & 1023) * 2;                   // this block: rows h, h+1
    int w = threadIdx.x;                        // 0..127

    const uint2* xb = xph + (size_t)b * HP * WP;          // SGPR base
    const unsigned* xbu = (const unsigned*)xb;
    float* outb = out + (size_t)(b * 2) * HH * WW;        // SGPR base

    // 4 rows x 3 cols f16 neighborhood (8B cells)
    uint2 nbc[4][3];
#pragma unroll
    for (int dy = 0; dy < 4; ++dy)
#pragma unroll
        for (int dx = 0; dx < 3; ++dx)
            nbc[dy][dx] = xb[(h + dy) * WP + (w + dx)];

    // pixel-pair f32 vectors (cvt from f16), static indexing
    f32x2 prs[3][3][4];
#pragma unroll
    for (int ky = 0; ky < 3; ++ky)
#pragma unroll
        for (int kx = 0; kx < 3; ++kx) {
            uint2 cA = nbc[ky][kx], cB = nbc[ky + 1][kx];
            prs[ky][kx][0] = (f32x2){hlo(cA.x), hlo(cB.x)};
            prs[ky][kx][1] = (f32x2){hhi(cA.x), hhi(cB.x)};
            prs[ky][kx][2] = (f32x2){hlo(cA.y), hlo(cB.y)};
            prs[ky][kx][3] = (f32x2){hhi(cA.y), hhi(cB.y)};
        }

    // ---- offset conv: r-outer, local accumulator -> v_pk_fma_f32 ----
    f32x2 off2[18];
#pragma unroll
    for (int r = 0; r < 18; ++r) {
        float bias = b_p[r];                    // uniform -> s_load (input buf)
        f32x2 s = (f32x2){bias, bias};
#pragma unroll
        for (int ky = 0; ky < 3; ++ky)
#pragma unroll
            for (int kx = 0; kx < 3; ++kx) {
                const float* wr = w_p + r * 36 + ky * 3 + kx;  // uniform s_load
                s += wr[0] * prs[ky][kx][0] + wr[9] * prs[ky][kx][1]
                   + wr[18] * prs[ky][kx][2] + wr[27] * prs[ky][kx][3];
            }
        off2[r] = s;
    }

    float acc0[2] = {0.f, 0.f};
    float acc1[2] = {0.f, 0.f};

#pragma unroll
    for (int g = 0; g < 3; ++g) {               // groups of 3 sampling points
        unsigned hg[3][2][4];                   // g-weight f16 splats
        bool adj[3][2];
        uint4a q0[3][2], q1[3][2];              // paired-row 16B loads

        // ---- phase 1+2: coords, g-weights, issue all 12 loads ----
#pragma unroll
        for (int j = 0; j < 3; ++j) {
            int n = g * 3 + j;
            int pny = n / 3 - 1;
            int pnx = n % 3 - 1;
            f32x2 py2 = (f32x2){(float)(h + 1 + pny), (float)(h + 2 + pny)} + off2[n];
            f32x2 px2 = (float)(w + 1 + pnx) + off2[9 + n];
            f32x2 fy2 = {floorf(py2.x), floorf(py2.y)};
            f32x2 fx2 = {floorf(px2.x), floorf(px2.y)};
            f32x2 y0f = {fminf(fmaxf(fy2.x, 0.f), (float)(HP - 1)),
                         fminf(fmaxf(fy2.y, 0.f), (float)(HP - 1))};
            f32x2 y1f = {fminf(fmaxf(fy2.x + 1.f, 0.f), (float)(HP - 1)),
                         fminf(fmaxf(fy2.y + 1.f, 0.f), (float)(HP - 1))};
            f32x2 x0f = {fminf(fmaxf(fx2.x, 0.f), (float)(WP - 1)),
                         fminf(fmaxf(fx2.y, 0.f), (float)(WP - 1))};
            f32x2 x1f = {fminf(fmaxf(fx2.x + 1.f, 0.f), (float)(WP - 1)),
                         fminf(fmaxf(fx2.y + 1.f, 0.f), (float)(WP - 1))};
            f32x2 pyc = {fminf(fmaxf(py2.x, 0.f), (float)(HP - 1)),
                         fminf(fmaxf(py2.y, 0.f), (float)(HP - 1))};
            f32x2 pxc = {fminf(fmaxf(px2.x, 0.f), (float)(WP - 1)),
                         fminf(fmaxf(px2.y, 0.f), (float)(WP - 1))};
            f32x2 ay = 1.f + (y0f - pyc);
            f32x2 by = 1.f - (y1f - pyc);
            f32x2 ax = 1.f + (x0f - pxc);
            f32x2 bx = 1.f - (x1f - pxc);
            f32x2 glt = ay * ax, grb = by * bx, glb = ay * bx, grt = by * ax;

#pragma unroll
            for (int p = 0; p < 2; ++p) {       // p compile-time
                int y0 = (int)(p ? y0f.y : y0f.x);
                int y1 = (int)(p ? y1f.y : y1f.x);
                int x0 = (int)(p ? x0f.y : x0f.x);
                int x1 = (int)(p ? x1f.y : x1f.x);
                float g_lt = p ? glt.y : glt.x;
                float g_rb = p ? grb.y : grb.x;
                float g_lb = p ? glb.y : glb.x;
                float g_rt = p ? grt.y : grt.x;
                hg[j][p][0] = pku(g_lt, g_lt);
                hg[j][p][1] = pku(g_rb, g_rb);
                hg[j][p][2] = pku(g_lb, g_lb);
                hg[j][p][3] = pku(g_rt, g_rt);
                adj[j][p] = (x1 > x0);
                q0[j][p] = *(const uint4a*)(xbu + 2 * (y0 * WP + x0));
                q1[j][p] = *(const uint4a*)(xbu + 2 * (y1 * WP + x0));
            }
        }

        // ---- phase 3: consume (select, f16 interp, dot2 combine) ----
#pragma unroll
        for (int j = 0; j < 3; ++j) {
            int n = g * 3 + j;
            unsigned wd00 = pku(w_dc[0 * 36 + 0 * 9 + n], w_dc[0 * 36 + 1 * 9 + n]);
            unsigned wd01 = pku(w_dc[0 * 36 + 2 * 9 + n], w_dc[0 * 36 + 3 * 9 + n]);
            unsigned wd10 = pku(w_dc[1 * 36 + 0 * 9 + n], w_dc[1 * 36 + 1 * 9 + n]);
            unsigned wd11 = pku(w_dc[1 * 36 + 2 * 9 + n], w_dc[1 * 36 + 3 * 9 + n]);
#pragma unroll
            for (int p = 0; p < 2; ++p) {
                uint4a a = q0[j][p], c = q1[j][p];
                bool ad = adj[j][p];
                unsigned lt01 = a.x, lt23 = a.y;
                unsigned lb01 = ad ? a.z : a.x, lb23 = ad ? a.w : a.y;
                unsigned rt01 = c.x, rt23 = c.y;
                unsigned rb01 = ad ? c.z : c.x, rb23 = ad ? c.w : c.y;

                half2v h01 = b2h(hg[j][p][0]) * b2h(lt01) + b2h(hg[j][p][1]) * b2h(rb01)
                           + b2h(hg[j][p][2]) * b2h(lb01) + b2h(hg[j][p][3]) * b2h(rt01);
                half2v h23 = b2h(hg[j][p][0]) * b2h(lt23) + b2h(hg[j][p][1]) * b2h(rb23)
                           + b2h(hg[j][p][2]) * b2h(lb23) + b2h(hg[j][p][3]) * b2h(rt23);

                acc0[p] = dot2(h01, wd00, acc0[p]);
                acc0[p] = dot2(h23, wd01, acc0[p]);
                acc1[p] = dot2(h01, wd10, acc1[p]);
                acc1[p] = dot2(h23, wd11, acc1[p]);
            }
        }
    }
#pragma unroll
    for (int p = 0; p < 2; ++p) {
        outb[(h + p) * WW + w] = acc0[p];
        outb[HH * WW + (h + p) * WW + w] = acc1[p];
    }
}

// ---------------------------------------------------------------------------
extern "C" void kernel_launch(void* const* d_in, const int* in_sizes, int n_in,
                              void* d_out, int out_size, void* d_ws, size_t ws_size,
                              hipStream_t stream) {
    const float* rgb  = (const float*)d_in[0];
    const float* sar  = (const float*)d_in[1];
    const float* w_fm = (const float*)d_in[2];
    const float* w_fs = (const float*)d_in[3];
    const float* w_p  = (const float*)d_in[4];
    const float* b_p  = (const float*)d_in[5];
    const float* w_dc = (const float*)d_in[6];
    float* out = (float*)d_out;

    // ws layout: fmp [65536 float2 = 131072 f32] | xph [BB*HP*WP uint2 + slack]
    float* ws = (float*)d_ws;
    float2* fmp = (float2*)ws;
    uint2* xph = (uint2*)(ws + 131072);                // 8B aligned

    k_fm<<<BB * 64, 128, 0, stream>>>(rgb, w_fm, fmp, xph);
    k_mat<<<BB * (HH / MROWS), 128, 0, stream>>>(rgb, sar, w_fs, fmp, xph);
    k_deform<<<BB * (HH / 2), 128, 0, stream>>>(w_p, b_p, w_dc, xph, out);
}